// Round 8
// baseline (531.130 us; speedup 1.0000x reference)
//
#include <hip/hip_runtime.h>
#include <hip/hip_bf16.h>

typedef short bs8 __attribute__((ext_vector_type(8)));
typedef short bs4 __attribute__((ext_vector_type(4)));
typedef float f32x4 __attribute__((ext_vector_type(4)));
typedef float f32x16 __attribute__((ext_vector_type(16)));
typedef int i32x4 __attribute__((ext_vector_type(4)));

#define B_ 4
#define L_ 2048
#define H_ 16
#define E_ 64
#define KT_ 64    // keys per staged tile (two 32-key halves, one per wave-group)
#define KSTR 72   // LDS stride (shorts) for K/V rows
#define SCSTR 68  // f32 stride for combine/transpose scratch
#define BUFB 18432  // bytes per staging buffer (K 9216 + V 9216)
#define NEG_INF (-1e30f)
#define SCALE_LOG2E (0.125f * 1.44269504088896340736f)

__device__ unsigned g_cnt;   // grid-barrier arrival counter (memset to 0 per launch)

__device__ __forceinline__ short bf16of(float x) {
  __hip_bfloat16 h = __float2bfloat16(x);
  return *reinterpret_cast<short*>(&h);
}
__device__ __forceinline__ unsigned pk2(float lo, float hi) {
  return (unsigned)(unsigned short)bf16of(lo) |
         ((unsigned)(unsigned short)bf16of(hi) << 16);
}

// ---------- Fused convert + flash-attention kernel ----------
// Single launch, grid 1024, 256 threads (4 waves), __launch_bounds__(256,4),
// LDS 36.9KB -> exactly 4 blocks/CU, grid == resident capacity -> all blocks
// co-resident at t=0 (r4 identity), so a manual device-scope grid barrier is
// safe (G12/G16: global atomicAdd is device-scope; __threadfence both sides).
//
// Stage A (convert): block (bh, p) converts keys [p*128,+128) of its own bh:
// K fp32 [b,s,h,e] -> bf16 Kb [bh,s,e]; V fp32 -> bf16 Vt [bh,e,s] via the
// prep kernel's verified packed-u32 LDS transpose. Writers == the 16 blocks
// that read this bh -> converted lines land in the reader XCD's L2.
// Stage B (flash): r7 structure (72us measured) + single-barrier LDS double
// buffering: write buf[cur^1] BEFORE computing buf[cur]; 1 barrier/tile
// (was 2); prefetch 2 tiles ahead.
//
// Block = 64 q-rows, pair {p, 31-p} in two phases: 33 tiles per block ->
// every block identical work (structural balance; no backfill exists).
// Wave (g,s): s = row strip [q0+32s,+32), g = key half [k0+32g,+32).
// Unnormalized exp2-domain partials combined across g via LDS at phase end.
// XCD decode: id&7 = XCD; each XCD works bh in [x*8, x*8+8) (4MB = L2).
//
// Swapped QK^T (T12): S^T = K.Q^T via mfma_32x32x16 (A=K from LDS, B=Q in
// regs) -> lane holds P^T[key][q=l32] for its 16 key-rows. Mask + raw
// v_exp_f32 + v_cvt_pk_bf16_f32 + 2x2 v_permlane32_swap (distinct-value
// operands only; identical inputs tie to one vreg -> vdst==src0 miscompile,
// the r3 inf bug). O^T = V^T.P^T (A=V^T from LDS). setprio(1) around MFMA
// clusters (T5; 4 independent blocks/CU).
// 32x32x16 layouts (m74/m101 verified):
//   A[m = lane&31][k = (lane>>5)*8 + j]
//   B[k = (lane>>5)*8 + j][n = lane&31]
//   C/D: col = lane&31, row = (reg&3) + 8*(reg>>2) + 4*(lane>>5)
__global__ __launch_bounds__(256, 4) void fused(const float* __restrict__ Q,
                                                const float* __restrict__ K,
                                                const float* __restrict__ V,
                                                short* __restrict__ Kb,
                                                short* __restrict__ Vt,
                                                float* __restrict__ O) {
  const int id  = blockIdx.x;
  const int xcd = id & 7;
  const int j   = id >> 3;               // 0..127 within XCD
  const int bh  = xcd * 8 + (j >> 4);
  const int p   = j & 15;                // pair {p, 31-p}; also convert slice
  const int b = bh >> 4, h = bh & 15;
  const int tid = threadIdx.x;
  const int w = tid >> 6;
  const int g = w >> 1;                  // key half-group: keys [k0+32g, +32)
  const int s = w & 1;                   // row strip
  const int lane = tid & 63;
  const int l32 = lane & 31;
  const int hh  = lane >> 5;
  const int h8  = hh * 8;

  // double staging buffers; scratch (17.7KB) and lt (9KB) union into buf0
  __shared__ __align__(16) char smem[2 * BUFB];

  // ======== Stage A: convert this block's K/V slice (keys [p*128,+128)) ======
  {
    const int kr0 = p * 128;
#pragma unroll
    for (int i = 0; i < 8; ++i) {
      const int gg = i * 256 + tid;          // 0..2047 float4s of the slice
      const int e4 = gg & 15, sloc = gg >> 4;
      const int ss = kr0 + sloc;
      float4 v = *(const float4*)(K + (((size_t)b * L_ + ss) * H_ + h) * E_ + e4 * 4);
      bs4 o;
      o.x = bf16of(v.x); o.y = bf16of(v.y); o.z = bf16of(v.z); o.w = bf16of(v.w);
      *(bs4*)(Kb + ((size_t)bh * L_ + ss) * E_ + e4 * 4) = o;
    }
    unsigned* lt = (unsigned*)smem;          // [64 e][35] packed 2x bf16
    for (int ch = 0; ch < 2; ++ch) {
      const int s0 = p * 128 + ch * 64;
#pragma unroll
      for (int i = 0; i < 2; ++i) {
        const int idx = i * 256 + tid;       // 0..511
        const int sp = idx >> 4, e4 = idx & 15;
        const float* p0 = V + (((size_t)b * L_ + s0 + 2 * sp) * H_ + h) * E_ + e4 * 4;
        float4 v0 = *(const float4*)p0;
        float4 v1 = *(const float4*)(p0 + H_ * E_);
        lt[(e4 * 4 + 0) * 35 + sp] = pk2(v0.x, v1.x);
        lt[(e4 * 4 + 1) * 35 + sp] = pk2(v0.y, v1.y);
        lt[(e4 * 4 + 2) * 35 + sp] = pk2(v0.z, v1.z);
        lt[(e4 * 4 + 3) * 35 + sp] = pk2(v0.w, v1.w);
      }
      __syncthreads();
#pragma unroll
      for (int i = 0; i < 2; ++i) {
        const int idx = i * 256 + tid;
        const int e = idx >> 3, s8 = idx & 7;
        uint4 o;
        o.x = lt[e * 35 + s8 * 4 + 0];
        o.y = lt[e * 35 + s8 * 4 + 1];
        o.z = lt[e * 35 + s8 * 4 + 2];
        o.w = lt[e * 35 + s8 * 4 + 3];
        *(uint4*)(Vt + ((size_t)bh * E_ + e) * L_ + s0 + 8 * s8) = o;
      }
      __syncthreads();
    }
  }

  // ======== grid barrier (all 1024 blocks co-resident by construction) ======
  __threadfence();                           // release converted K/V
  if (tid == 0) {
    __hip_atomic_fetch_add(&g_cnt, 1u, __ATOMIC_ACQ_REL, __HIP_MEMORY_SCOPE_AGENT);
    while (__hip_atomic_load(&g_cnt, __ATOMIC_ACQUIRE, __HIP_MEMORY_SCOPE_AGENT) < 1024u)
      __builtin_amdgcn_s_sleep(2);
  }
  __syncthreads();
  __threadfence();                           // acquire other blocks' writes

  // ======== Stage B: flash attention ========
  const short* KbBase = Kb + (size_t)bh * L_ * E_;
  const short* VtBase = Vt + (size_t)bh * E_ * L_;
  const int sr = tid >> 3;                   // staging rows sr, sr+32
  const int sc8 = (tid & 7) * 8;             // staging cols sc8..sc8+7
  float* scb = (float*)smem;                 // combine scratch (unions buf0)

  for (int phase = 0; phase < 2; ++phase) {
    const int qt  = phase ? (31 - p) : p;
    const int q0w = qt * 64 + 32 * s;        // this wave's first q row
    const int nkt = qt + 1;

    // ---- Q B-frags: aQ[ks] covers dims ks*16 + h8 .. +7 (pre-scaled) ----
    bs8 aQ[4];
    {
      const float* qp = Q + (((size_t)b * L_ + q0w + l32) * H_ + h) * E_ + h8;
#pragma unroll
      for (int ks = 0; ks < 4; ++ks) {
        float4 f0 = *(const float4*)(qp + ks * 16);
        float4 f1 = *(const float4*)(qp + ks * 16 + 4);
        bs8 a;
        a[0] = bf16of(f0.x * SCALE_LOG2E); a[1] = bf16of(f0.y * SCALE_LOG2E);
        a[2] = bf16of(f0.z * SCALE_LOG2E); a[3] = bf16of(f0.w * SCALE_LOG2E);
        a[4] = bf16of(f1.x * SCALE_LOG2E); a[5] = bf16of(f1.y * SCALE_LOG2E);
        a[6] = bf16of(f1.z * SCALE_LOG2E); a[7] = bf16of(f1.w * SCALE_LOG2E);
        aQ[ks] = a;
      }
    }

    f32x16 accO[2];            // O^T partial (this g's keys): [dsub]
#pragma unroll
    for (int d = 0; d < 2; ++d)
#pragma unroll
      for (int r = 0; r < 16; ++r) accO[d][r] = 0.f;
    float accL = 0.f;          // denominator partial

    // ---- prologue: stage tile 0 into buf0, prefetch tile 1 ----
    __syncthreads();   // prior-phase scratch / conversion lt reads complete
    bs8 pfK[2], pfV[2];
#pragma unroll
    for (int i = 0; i < 2; ++i) {
      pfK[i] = *(const bs8*)(KbBase + (size_t)(sr + 32 * i) * E_ + sc8);
      pfV[i] = *(const bs8*)(VtBase + (size_t)(sr + 32 * i) * L_ + sc8);
    }
    {
      short* nK = (short*)smem;
      short* nV = (short*)(smem + 9216);
#pragma unroll
      for (int i = 0; i < 2; ++i) {
        *(bs8*)&nK[(sr + 32 * i) * KSTR + sc8] = pfK[i];
        *(bs8*)&nV[(sr + 32 * i) * KSTR + sc8] = pfV[i];
      }
    }
    if (nkt > 1) {
#pragma unroll
      for (int i = 0; i < 2; ++i) {
        pfK[i] = *(const bs8*)(KbBase + (size_t)(KT_ + sr + 32 * i) * E_ + sc8);
        pfV[i] = *(const bs8*)(VtBase + (size_t)(sr + 32 * i) * L_ + KT_ + sc8);
      }
    }
    __syncthreads();   // buf0 ready
    int cur = 0;

    for (int kt = 0; kt < nkt; ++kt) {
      short* cK = (short*)(smem + cur * BUFB);
      short* cV = (short*)(smem + cur * BUFB + 9216);
      // write NEXT tile into the other buffer (its last readers finished at
      // the barrier ending iteration kt-1), then prefetch tile kt+2
      if (kt + 1 < nkt) {
        short* nK = (short*)(smem + (cur ^ 1) * BUFB);
        short* nV = (short*)(smem + (cur ^ 1) * BUFB + 9216);
#pragma unroll
        for (int i = 0; i < 2; ++i) {
          *(bs8*)&nK[(sr + 32 * i) * KSTR + sc8] = pfK[i];
          *(bs8*)&nV[(sr + 32 * i) * KSTR + sc8] = pfV[i];
        }
        if (kt + 2 < nkt) {
          const int kn = (kt + 2) * KT_;
#pragma unroll
          for (int i = 0; i < 2; ++i) {
            pfK[i] = *(const bs8*)(KbBase + (size_t)(kn + sr + 32 * i) * E_ + sc8);
            pfV[i] = *(const bs8*)(VtBase + (size_t)(sr + 32 * i) * L_ + kn + sc8);
          }
        }
      }

      const int kb = kt * KT_ + 32 * g;    // this wave's 32-key half
      if (kb <= q0w + 31) {                // not fully masked
        const bool diag = (kb + 31 > q0w);

        // ---- S^T = K.Q^T on this half ----
        f32x16 cc;
#pragma unroll
        for (int r = 0; r < 16; ++r) cc[r] = 0.f;
        __builtin_amdgcn_s_setprio(1);
#pragma unroll
        for (int ks = 0; ks < 4; ++ks) {
          bs8 aK = *(const bs8*)&cK[(32 * g + l32) * KSTR + ks * 16 + h8];
          cc = __builtin_amdgcn_mfma_f32_32x32x16_bf16(aK, aQ[ks], cc, 0, 0, 0);
        }
        __builtin_amdgcn_s_setprio(0);
        if (diag) {
          const int qcol = q0w + l32;
#pragma unroll
          for (int r = 0; r < 16; ++r) {
            const int key = kb + ((r & 3) + 8 * (r >> 2) + 4 * hh);
            if (key > qcol) cc[r] = NEG_INF;
          }
        }
        // ---- exp2 (raw v_exp_f32), denominator, pack (cvt_pk) ----
        float pv[16];
#pragma unroll
        for (int r = 0; r < 16; ++r) pv[r] = __builtin_amdgcn_exp2f(cc[r]);
        accL += ((((pv[0] + pv[1]) + (pv[2] + pv[3])) + ((pv[4] + pv[5]) + (pv[6] + pv[7]))) +
                 (((pv[8] + pv[9]) + (pv[10] + pv[11])) + ((pv[12] + pv[13]) + (pv[14] + pv[15]))));
        unsigned pk[8];
#pragma unroll
        for (int i = 0; i < 8; ++i)
          asm("v_cvt_pk_bf16_f32 %0, %1, %2"
              : "=v"(pk[i]) : "v"(pv[2 * i]), "v"(pv[2 * i + 1]));
        unsigned w0 = pk[0], w2 = pk[2];
        asm("v_permlane32_swap_b32 %0, %1" : "+v"(w0), "+v"(w2));
        unsigned w1 = pk[1], w3 = pk[3];
        asm("v_permlane32_swap_b32 %0, %1" : "+v"(w1), "+v"(w3));
        unsigned w4 = pk[4], w6 = pk[6];
        asm("v_permlane32_swap_b32 %0, %1" : "+v"(w4), "+v"(w6));
        unsigned w5 = pk[5], w7 = pk[7];
        asm("v_permlane32_swap_b32 %0, %1" : "+v"(w5), "+v"(w7));
        i32x4 f0 = {(int)w0, (int)w1, (int)w2, (int)w3};
        i32x4 f1 = {(int)w4, (int)w5, (int)w6, (int)w7};
        bs8 pB0 = *(bs8*)&f0;
        bs8 pB1 = *(bs8*)&f1;

        // ---- O^T += V^T . P^T (this g's 32 keys) ----
        __builtin_amdgcn_s_setprio(1);
#pragma unroll
        for (int dsub = 0; dsub < 2; ++dsub) {
          bs8 aV0 = *(const bs8*)&cV[(dsub * 32 + l32) * KSTR + 32 * g + h8];
          bs8 aV1 = *(const bs8*)&cV[(dsub * 32 + l32) * KSTR + 32 * g + 16 + h8];
          accO[dsub] = __builtin_amdgcn_mfma_f32_32x32x16_bf16(aV0, pB0, accO[dsub], 0, 0, 0);
          accO[dsub] = __builtin_amdgcn_mfma_f32_32x32x16_bf16(aV1, pB1, accO[dsub], 0, 0, 0);
        }
        __builtin_amdgcn_s_setprio(0);
      }
      __syncthreads();   // readers of buf[cur] done; buf[cur^1] (tile kt+1) ready
      cur ^= 1;
    }

    // ---- combine across g (unnormalized partials add exactly), store ----
    const float Lf = accL + __shfl_xor(accL, 32, 64);
    float* scbO = scb + s * (32 * SCSTR);
    float* scbL = scb + 2 * (32 * SCSTR) + s * 32;
    if (g == 1) {
#pragma unroll
      for (int dsub = 0; dsub < 2; ++dsub)
#pragma unroll
        for (int q4 = 0; q4 < 4; ++q4) {
          f32x4 vv = {accO[dsub][4 * q4 + 0], accO[dsub][4 * q4 + 1],
                      accO[dsub][4 * q4 + 2], accO[dsub][4 * q4 + 3]};
          *(f32x4*)&scbO[(size_t)l32 * SCSTR + dsub * 32 + 8 * q4 + 4 * hh] = vv;
        }
      if (hh == 0) scbL[l32] = Lf;
    }
    __syncthreads();
    if (g == 0) {
      const float inv = 1.f / (Lf + scbL[l32]);
#pragma unroll
      for (int dsub = 0; dsub < 2; ++dsub)
#pragma unroll
        for (int q4 = 0; q4 < 4; ++q4) {
          float* ptr = &scbO[(size_t)l32 * SCSTR + dsub * 32 + 8 * q4 + 4 * hh];
          f32x4 ov = *(const f32x4*)ptr;
          f32x4 vv = {(accO[dsub][4 * q4 + 0] + ov.x) * inv,
                      (accO[dsub][4 * q4 + 1] + ov.y) * inv,
                      (accO[dsub][4 * q4 + 2] + ov.z) * inv,
                      (accO[dsub][4 * q4 + 3] + ov.w) * inv};
          *(f32x4*)ptr = vv;
        }
      // transposed coalesced store: 4 full q-rows per instruction
#pragma unroll
      for (int jj = 0; jj < 8; ++jj) {
        const int qq = jj * 4 + (lane >> 4);
        const int d0 = (lane & 15) * 4;
        f32x4 ov = *(const f32x4*)&scbO[(size_t)qq * SCSTR + d0];
        float* op = O + (((size_t)b * L_ + qt * 64 + 32 * s + qq) * H_ + h) * E_ + d0;
        *(f32x4*)op = ov;
      }
    }
  }
}

extern "C" void kernel_launch(void* const* d_in, const int* in_sizes, int n_in,
                              void* d_out, int out_size, void* d_ws, size_t ws_size,
                              hipStream_t stream) {
  (void)in_sizes; (void)n_in; (void)out_size; (void)ws_size;
  const float* Q = (const float*)d_in[0];
  const float* K = (const float*)d_in[1];
  const float* V = (const float*)d_in[2];
  float* Out = (float*)d_out;
  short* Kb = (short*)d_ws;                              // 16.78 MB
  short* Vt = Kb + (size_t)B_ * H_ * L_ * E_;            // +16.78 MB

  static void* cnt_addr = nullptr;
  if (!cnt_addr) (void)hipGetSymbolAddress(&cnt_addr, HIP_SYMBOL(g_cnt));
  hipMemsetAsync(cnt_addr, 0, sizeof(unsigned), stream);   // capture-legal node
  fused<<<1024, 256, 0, stream>>>(Q, K, V, Kb, Vt, Out);
}

// Round 9
// 334.827 us; speedup vs baseline: 1.5863x; 1.5863x over previous
//
#include <hip/hip_runtime.h>
#include <hip/hip_bf16.h>

typedef short bs8 __attribute__((ext_vector_type(8)));
typedef short bs4 __attribute__((ext_vector_type(4)));
typedef float f32x4 __attribute__((ext_vector_type(4)));
typedef float f32x16 __attribute__((ext_vector_type(16)));
typedef int i32x4 __attribute__((ext_vector_type(4)));

#define B_ 4
#define L_ 2048
#define H_ 16
#define E_ 64
#define KT_ 64    // keys per logical tile (two 32-key halves, one per wave-group)
#define SCSTR 68  // f32 stride for combine/transpose scratch
#define NEG_INF (-1e30f)
#define SCALE_LOG2E (0.125f * 1.44269504088896340736f)

__device__ __forceinline__ short bf16of(float x) {
  __hip_bfloat16 h = __float2bfloat16(x);
  return *reinterpret_cast<short*>(&h);
}

// ---------- Fused prepass (r7 verbatim) ----------
// blocks [0,1024):    K fp32 [b,s,h,e] -> bf16 Kb [bh,s,e]   (grid-stride x8)
// blocks [1024,3072): V fp32 [b,s,h,e] -> bf16 Vt [bh,e,s]   (packed-u32 LDS transpose)
__global__ __launch_bounds__(256) void prep(const float* __restrict__ K,
                                            const float* __restrict__ V,
                                            short* __restrict__ Kb,
                                            short* __restrict__ Vt) {
  __shared__ unsigned int lt[64 * 35];   // [e][s_pair] packed 2x bf16
  const int tid = threadIdx.x;
  if (blockIdx.x < 1024) {
    size_t base = (size_t)blockIdx.x * 256 + tid;
#pragma unroll
    for (int i = 0; i < 8; ++i) {
      size_t g = base + (size_t)i * 262144;   // float4 index
      int e4 = g & 15;
      int h  = (g >> 4) & 15;
      int s  = (g >> 8) & 2047;
      int b  = (int)(g >> 19);
      float4 v = *(const float4*)(K + g * 4);
      bs4 o;
      o.x = bf16of(v.x); o.y = bf16of(v.y); o.z = bf16of(v.z); o.w = bf16of(v.w);
      *(bs4*)(Kb + (((size_t)(b * 16 + h) * L_ + s) * E_ + e4 * 4)) = o;
    }
  } else {
    int vb = blockIdx.x - 1024;   // 0..2047
    int st = vb & 31, bh = vb >> 5;
    int b = bh >> 4, h = bh & 15;
    int s0 = st * 64;
#pragma unroll
    for (int i = 0; i < 2; ++i) {
      int idx = i * 256 + tid;       // 0..511
      int sp = idx >> 4;             // s-pair 0..31
      int e4 = idx & 15;
      const float* p0 = V + (((size_t)b * L_ + s0 + 2 * sp) * H_ + h) * E_ + e4 * 4;
      float4 v0 = *(const float4*)p0;
      float4 v1 = *(const float4*)(p0 + H_ * E_);
      unsigned u;
      u = (unsigned short)bf16of(v0.x) | ((unsigned)(unsigned short)bf16of(v1.x) << 16);
      lt[(e4 * 4 + 0) * 35 + sp] = u;
      u = (unsigned short)bf16of(v0.y) | ((unsigned)(unsigned short)bf16of(v1.y) << 16);
      lt[(e4 * 4 + 1) * 35 + sp] = u;
      u = (unsigned short)bf16of(v0.z) | ((unsigned)(unsigned short)bf16of(v1.z) << 16);
      lt[(e4 * 4 + 2) * 35 + sp] = u;
      u = (unsigned short)bf16of(v0.w) | ((unsigned)(unsigned short)bf16of(v1.w) << 16);
      lt[(e4 * 4 + 3) * 35 + sp] = u;
    }
    __syncthreads();
#pragma unroll
    for (int i = 0; i < 2; ++i) {
      int idx = i * 256 + tid;
      int e  = idx >> 3;             // 0..63
      int s8 = idx & 7;              // 8-key group
      uint4 o;
      o.x = lt[e * 35 + s8 * 4 + 0];
      o.y = lt[e * 35 + s8 * 4 + 1];
      o.z = lt[e * 35 + s8 * 4 + 2];
      o.w = lt[e * 35 + s8 * 4 + 3];
      *(uint4*)(Vt + ((size_t)bh * E_ + e) * L_ + s0 + 8 * s8) = o;
    }
  }
}

// ---------- Main flash-attention kernel ----------
// r9 = r7's grid/pairing/swapped-core/epilogue, but NO LDS staging at all:
// K-fragments register-prefetched ONE TILE AHEAD (named A/B sets, unroll-by-2
// K-loop, static indexing per rule #20); V-fragments issued at tile start and
// consumed ~400 cycles later (after QK^T + softmax) -- self-hiding.
// This deletes the LDS pipe's ~32us of staging traffic (the largest per-CU
// consumer in r7) and BOTH K-loop barriers; waves are fully independent.
// r6 failed at this because it had NO prefetch (serial L2 chains); r7 hid
// latency via LDS+barriers; r9 hides it in registers with zero barriers.
// exp2 done in-place in cc (saves 16 VGPR; ~120 peak under the (256,4)=128
// cap). Per-XCD L2 frag traffic ~2.1 TB/s < 4.3 TB/s ceiling.
//
// Grid 1024, 256 threads (4 waves). Block = 64 q-rows, pair {p, 31-p} in two
// phases: 33 tiles per block -> every block identical work (grid == resident
// capacity, no backfill). 4 blocks/CU resident = 16 waves/CU.
// Wave (g,s): s = row strip [q0+32s,+32), g = key half [k0+32g,+32).
// Unnormalized exp2-domain partials combined across g via LDS at phase end.
// XCD decode: id&7 = XCD; each XCD works bh in [x*8, x*8+8) (4MB = L2).
//
// Swapped QK^T (T12): S^T = K.Q^T via mfma_32x32x16 (A=K regs, B=Q regs) ->
// lane holds P^T[key][q=l32] for its 16 key-rows. Mask + raw v_exp_f32 +
// v_cvt_pk_bf16_f32 + 2x2 v_permlane32_swap (distinct-value operands only;
// identical inputs tie to one vreg -> vdst==src0 miscompile, the r3 inf
// bug). O^T = V^T.P^T. setprio(1) around MFMA clusters (T5).
// 32x32x16 layouts (m74/m101 verified):
//   A[m = lane&31][k = (lane>>5)*8 + j]
//   B[k = (lane>>5)*8 + j][n = lane&31]
//   C/D: col = lane&31, row = (reg&3) + 8*(reg>>2) + 4*(lane>>5)
__global__ __launch_bounds__(256, 4) void flash_fwd(const float* __restrict__ Q,
                                                    const short* __restrict__ Kb,
                                                    const short* __restrict__ Vt,
                                                    float* __restrict__ O) {
  const int id  = blockIdx.x;
  const int xcd = id & 7;
  const int j   = id >> 3;               // 0..127 within XCD
  const int bh  = xcd * 8 + (j >> 4);
  const int p   = j & 15;                // pair {p, 31-p}
  const int b = bh >> 4, h = bh & 15;
  const int tid = threadIdx.x;
  const int w = tid >> 6;
  const int g = w >> 1;                  // key half-group: keys [k0+32g, +32)
  const int s = w & 1;                   // row strip
  const int lane = tid & 63;
  const int l32 = lane & 31;
  const int hh  = lane >> 5;
  const int h8  = hh * 8;

  __shared__ float scb[2 * 32 * SCSTR + 64];   // combine/transpose scratch only

  const short* KbBase = Kb + (size_t)bh * L_ * E_;
  const short* VtBase = Vt + (size_t)bh * E_ * L_;
  const short* vRow0 = VtBase + (size_t)l32 * L_ + h8;         // dim row l32
  const short* vRow1 = VtBase + (size_t)(32 + l32) * L_ + h8;  // dim row 32+l32

  for (int phase = 0; phase < 2; ++phase) {
    const int qt  = phase ? (31 - p) : p;
    const int q0w = qt * 64 + 32 * s;    // this wave's first q row
    const int nkt = qt + 1;

    // ---- Q B-frags: aQ[ks] covers dims ks*16 + h8 .. +7 (pre-scaled) ----
    bs8 aQ[4];
    {
      const float* qp = Q + (((size_t)b * L_ + q0w + l32) * H_ + h) * E_ + h8;
#pragma unroll
      for (int ks = 0; ks < 4; ++ks) {
        float4 f0 = *(const float4*)(qp + ks * 16);
        float4 f1 = *(const float4*)(qp + ks * 16 + 4);
        bs8 a;
        a[0] = bf16of(f0.x * SCALE_LOG2E); a[1] = bf16of(f0.y * SCALE_LOG2E);
        a[2] = bf16of(f0.z * SCALE_LOG2E); a[3] = bf16of(f0.w * SCALE_LOG2E);
        a[4] = bf16of(f1.x * SCALE_LOG2E); a[5] = bf16of(f1.y * SCALE_LOG2E);
        a[6] = bf16of(f1.z * SCALE_LOG2E); a[7] = bf16of(f1.w * SCALE_LOG2E);
        aQ[ks] = a;
      }
    }

    f32x16 accO[2];            // O^T partial (this g's keys): [dsub]
#pragma unroll
    for (int d = 0; d < 2; ++d)
#pragma unroll
      for (int r = 0; r < 16; ++r) accO[d][r] = 0.f;
    float accL = 0.f;          // denominator partial

    // K-frag loader: 4x bs8 from global (L2-hot) into a NAMED reg set
    auto loadK = [&](int kt, bs8 fk[4]) {
      const int kb = kt * KT_ + 32 * g;
      const short* kp = KbBase + (size_t)(kb + l32) * E_ + h8;
      fk[0] = *(const bs8*)(kp);
      fk[1] = *(const bs8*)(kp + 16);
      fk[2] = *(const bs8*)(kp + 32);
      fk[3] = *(const bs8*)(kp + 48);
    };

    // full per-tile compute; V-frags issued first (consumed ~400cyc later)
    auto compute = [&](int kt, const bs8 fk[4]) {
      const int kb = kt * KT_ + 32 * g;
      if (kb > q0w + 31) return;           // fully masked (only g=1,s=0 last tile)
      const bool diag = (kb + 31 > q0w);
      // V^T frags: issue loads now, use after QK^T+softmax
      bs8 fV0 = *(const bs8*)(vRow0 + kb);
      bs8 fV1 = *(const bs8*)(vRow0 + kb + 16);
      bs8 fV2 = *(const bs8*)(vRow1 + kb);
      bs8 fV3 = *(const bs8*)(vRow1 + kb + 16);

      // ---- S^T = K.Q^T on this half ----
      f32x16 cc;
#pragma unroll
      for (int r = 0; r < 16; ++r) cc[r] = 0.f;
      __builtin_amdgcn_s_setprio(1);
      cc = __builtin_amdgcn_mfma_f32_32x32x16_bf16(fk[0], aQ[0], cc, 0, 0, 0);
      cc = __builtin_amdgcn_mfma_f32_32x32x16_bf16(fk[1], aQ[1], cc, 0, 0, 0);
      cc = __builtin_amdgcn_mfma_f32_32x32x16_bf16(fk[2], aQ[2], cc, 0, 0, 0);
      cc = __builtin_amdgcn_mfma_f32_32x32x16_bf16(fk[3], aQ[3], cc, 0, 0, 0);
      __builtin_amdgcn_s_setprio(0);
      if (diag) {
        const int qcol = q0w + l32;
#pragma unroll
        for (int r = 0; r < 16; ++r) {
          const int key = kb + ((r & 3) + 8 * (r >> 2) + 4 * hh);
          if (key > qcol) cc[r] = NEG_INF;
        }
      }
      // ---- exp2 in place (raw v_exp_f32), denominator, pack (cvt_pk) ----
#pragma unroll
      for (int r = 0; r < 16; ++r) cc[r] = __builtin_amdgcn_exp2f(cc[r]);
      accL += ((((cc[0] + cc[1]) + (cc[2] + cc[3])) + ((cc[4] + cc[5]) + (cc[6] + cc[7]))) +
               (((cc[8] + cc[9]) + (cc[10] + cc[11])) + ((cc[12] + cc[13]) + (cc[14] + cc[15]))));
      unsigned pk[8];
#pragma unroll
      for (int i = 0; i < 8; ++i)
        asm("v_cvt_pk_bf16_f32 %0, %1, %2"
            : "=v"(pk[i]) : "v"(cc[2 * i]), "v"(cc[2 * i + 1]));
      unsigned w0 = pk[0], w2 = pk[2];
      asm("v_permlane32_swap_b32 %0, %1" : "+v"(w0), "+v"(w2));
      unsigned w1 = pk[1], w3 = pk[3];
      asm("v_permlane32_swap_b32 %0, %1" : "+v"(w1), "+v"(w3));
      unsigned w4 = pk[4], w6 = pk[6];
      asm("v_permlane32_swap_b32 %0, %1" : "+v"(w4), "+v"(w6));
      unsigned w5 = pk[5], w7 = pk[7];
      asm("v_permlane32_swap_b32 %0, %1" : "+v"(w5), "+v"(w7));
      i32x4 f0 = {(int)w0, (int)w1, (int)w2, (int)w3};
      i32x4 f1 = {(int)w4, (int)w5, (int)w6, (int)w7};
      bs8 pB0 = *(bs8*)&f0;
      bs8 pB1 = *(bs8*)&f1;

      // ---- O^T += V^T . P^T (this g's 32 keys) ----
      __builtin_amdgcn_s_setprio(1);
      accO[0] = __builtin_amdgcn_mfma_f32_32x32x16_bf16(fV0, pB0, accO[0], 0, 0, 0);
      accO[0] = __builtin_amdgcn_mfma_f32_32x32x16_bf16(fV1, pB1, accO[0], 0, 0, 0);
      accO[1] = __builtin_amdgcn_mfma_f32_32x32x16_bf16(fV2, pB0, accO[1], 0, 0, 0);
      accO[1] = __builtin_amdgcn_mfma_f32_32x32x16_bf16(fV3, pB1, accO[1], 0, 0, 0);
      __builtin_amdgcn_s_setprio(0);
    };

    // ---- K-loop: unroll-by-2 with named A/B prefetch sets (rule #20) ----
    bs8 kA[4], kB[4];
    loadK(0, kA);
    int kt = 0;
    while (kt + 1 < nkt) {
      loadK(kt + 1, kB);          // prefetch next while computing current
      compute(kt, kA);
      if (kt + 2 < nkt) loadK(kt + 2, kA);
      compute(kt + 1, kB);
      kt += 2;
    }
    if (kt < nkt) compute(kt, kA);

    // ---- combine across g (unnormalized partials add exactly), store ----
    const float Lf = accL + __shfl_xor(accL, 32, 64);
    __syncthreads();   // prior phase's scratch reads complete before re-write
    float* scbO = scb + s * (32 * SCSTR);
    float* scbL = scb + 2 * (32 * SCSTR) + s * 32;
    if (g == 1) {
#pragma unroll
      for (int dsub = 0; dsub < 2; ++dsub)
#pragma unroll
        for (int q4 = 0; q4 < 4; ++q4) {
          f32x4 vv = {accO[dsub][4 * q4 + 0], accO[dsub][4 * q4 + 1],
                      accO[dsub][4 * q4 + 2], accO[dsub][4 * q4 + 3]};
          *(f32x4*)&scbO[(size_t)l32 * SCSTR + dsub * 32 + 8 * q4 + 4 * hh] = vv;
        }
      if (hh == 0) scbL[l32] = Lf;
    }
    __syncthreads();
    if (g == 0) {
      const float inv = 1.f / (Lf + scbL[l32]);
#pragma unroll
      for (int dsub = 0; dsub < 2; ++dsub)
#pragma unroll
        for (int q4 = 0; q4 < 4; ++q4) {
          float* ptr = &scbO[(size_t)l32 * SCSTR + dsub * 32 + 8 * q4 + 4 * hh];
          f32x4 ov = *(const f32x4*)ptr;
          f32x4 vv = {(accO[dsub][4 * q4 + 0] + ov.x) * inv,
                      (accO[dsub][4 * q4 + 1] + ov.y) * inv,
                      (accO[dsub][4 * q4 + 2] + ov.z) * inv,
                      (accO[dsub][4 * q4 + 3] + ov.w) * inv};
          *(f32x4*)ptr = vv;
        }
      // transposed coalesced store: 4 full q-rows per instruction
#pragma unroll
      for (int jj = 0; jj < 8; ++jj) {
        const int qq = jj * 4 + (lane >> 4);
        const int d0 = (lane & 15) * 4;
        f32x4 ov = *(const f32x4*)&scb[s * (32 * SCSTR) + (size_t)qq * SCSTR + d0];
        float* op = O + (((size_t)b * L_ + qt * 64 + 32 * s + qq) * H_ + h) * E_ + d0;
        *(f32x4*)op = ov;
      }
    }
  }
}

extern "C" void kernel_launch(void* const* d_in, const int* in_sizes, int n_in,
                              void* d_out, int out_size, void* d_ws, size_t ws_size,
                              hipStream_t stream) {
  (void)in_sizes; (void)n_in; (void)out_size; (void)ws_size;
  const float* Q = (const float*)d_in[0];
  const float* K = (const float*)d_in[1];
  const float* V = (const float*)d_in[2];
  float* Out = (float*)d_out;
  short* Kb = (short*)d_ws;                              // 16.78 MB
  short* Vt = Kb + (size_t)B_ * H_ * L_ * E_;            // +16.78 MB

  prep<<<1024 + 2048, 256, 0, stream>>>(K, V, Kb, Vt);
  flash_fwd<<<1024, 256, 0, stream>>>(Q, Kb, Vt, Out);
}

// Round 10
// 194.133 us; speedup vs baseline: 2.7359x; 1.7247x over previous
//
#include <hip/hip_runtime.h>
#include <hip/hip_bf16.h>

typedef short bs8 __attribute__((ext_vector_type(8)));
typedef short bs4 __attribute__((ext_vector_type(4)));
typedef float f32x4 __attribute__((ext_vector_type(4)));
typedef float f32x16 __attribute__((ext_vector_type(16)));
typedef int i32x4 __attribute__((ext_vector_type(4)));

#define B_ 4
#define L_ 2048
#define H_ 16
#define E_ 64
#define KT_ 64    // keys per staged tile (two 32-key halves, one per wave-group)
#define KSTR 72   // LDS stride (shorts) for K/V rows
#define SCSTR 68  // f32 stride for combine/transpose scratch
#define BUFB 18432  // bytes per staging buffer (K 9216 + V 9216)
#define NEG_INF (-1e30f)
#define SCALE_LOG2E (0.125f * 1.44269504088896340736f)

__device__ __forceinline__ short bf16of(float x) {
  __hip_bfloat16 h = __float2bfloat16(x);
  return *reinterpret_cast<short*>(&h);
}

// ---------- Fused prepass (r7 verbatim) ----------
// blocks [0,1024):    K fp32 [b,s,h,e] -> bf16 Kb [bh,s,e]   (grid-stride x8)
// blocks [1024,3072): V fp32 [b,s,h,e] -> bf16 Vt [bh,e,s]   (packed-u32 LDS transpose)
__global__ __launch_bounds__(256) void prep(const float* __restrict__ K,
                                            const float* __restrict__ V,
                                            short* __restrict__ Kb,
                                            short* __restrict__ Vt) {
  __shared__ unsigned int lt[64 * 35];   // [e][s_pair] packed 2x bf16
  const int tid = threadIdx.x;
  if (blockIdx.x < 1024) {
    size_t base = (size_t)blockIdx.x * 256 + tid;
#pragma unroll
    for (int i = 0; i < 8; ++i) {
      size_t g = base + (size_t)i * 262144;   // float4 index
      int e4 = g & 15;
      int h  = (g >> 4) & 15;
      int s  = (g >> 8) & 2047;
      int b  = (int)(g >> 19);
      float4 v = *(const float4*)(K + g * 4);
      bs4 o;
      o.x = bf16of(v.x); o.y = bf16of(v.y); o.z = bf16of(v.z); o.w = bf16of(v.w);
      *(bs4*)(Kb + (((size_t)(b * 16 + h) * L_ + s) * E_ + e4 * 4)) = o;
    }
  } else {
    int vb = blockIdx.x - 1024;   // 0..2047
    int st = vb & 31, bh = vb >> 5;
    int b = bh >> 4, h = bh & 15;
    int s0 = st * 64;
#pragma unroll
    for (int i = 0; i < 2; ++i) {
      int idx = i * 256 + tid;       // 0..511
      int sp = idx >> 4;             // s-pair 0..31
      int e4 = idx & 15;
      const float* p0 = V + (((size_t)b * L_ + s0 + 2 * sp) * H_ + h) * E_ + e4 * 4;
      float4 v0 = *(const float4*)p0;
      float4 v1 = *(const float4*)(p0 + H_ * E_);
      unsigned u;
      u = (unsigned short)bf16of(v0.x) | ((unsigned)(unsigned short)bf16of(v1.x) << 16);
      lt[(e4 * 4 + 0) * 35 + sp] = u;
      u = (unsigned short)bf16of(v0.y) | ((unsigned)(unsigned short)bf16of(v1.y) << 16);
      lt[(e4 * 4 + 1) * 35 + sp] = u;
      u = (unsigned short)bf16of(v0.z) | ((unsigned)(unsigned short)bf16of(v1.z) << 16);
      lt[(e4 * 4 + 2) * 35 + sp] = u;
      u = (unsigned short)bf16of(v0.w) | ((unsigned)(unsigned short)bf16of(v1.w) << 16);
      lt[(e4 * 4 + 3) * 35 + sp] = u;
    }
    __syncthreads();
#pragma unroll
    for (int i = 0; i < 2; ++i) {
      int idx = i * 256 + tid;
      int e  = idx >> 3;             // 0..63
      int s8 = idx & 7;              // 8-key group
      uint4 o;
      o.x = lt[e * 35 + s8 * 4 + 0];
      o.y = lt[e * 35 + s8 * 4 + 1];
      o.z = lt[e * 35 + s8 * 4 + 2];
      o.w = lt[e * 35 + s8 * 4 + 3];
      *(uint4*)(Vt + ((size_t)bh * E_ + e) * L_ + s0 + 8 * s8) = o;
    }
  }
}

// ---------- Main flash-attention kernel ----------
// r10 = r7's verified structure (72us flash) + r8's Stage-B single-barrier
// LDS double-buffer (numerics verified in r8; r8's regression was the grid
// spin-barrier, not this). One __syncthreads per tile (was 2): next tile's
// staging writes land in buf[cur^1] BEFORE computing buf[cur]; the tile-end
// barrier simultaneously retires buf[cur] readers and publishes buf[cur^1].
// Global prefetch reaches 2 tiles ahead (issue-early / write-late, G15).
// r9 lesson: direct-global frags spill at 4 blocks/CU (WRITE 106MB) -- LDS
// staging is the correct latency decoupler; reduce its barrier cost instead.
//
// Grid 1024, 256 threads (4 waves). Block = 64 q-rows, pair {p, 31-p} in two
// phases: 33 tiles per block -> every block identical work (grid == resident
// capacity, no backfill). 4 blocks/CU resident = 16 waves/CU; LDS 36.9KB.
// Wave (g,s): s = row strip [q0+32s,+32), g = key half [k0+32g,+32).
// Unnormalized exp2-domain partials combined across g via LDS at phase end.
// XCD decode: id&7 = XCD; each XCD works bh in [x*8, x*8+8) (4MB = L2).
//
// Swapped QK^T (T12): S^T = K.Q^T via mfma_32x32x16 (A=K from LDS, B=Q in
// regs) -> lane holds P^T[key][q=l32] for its 16 key-rows. Mask + raw
// v_exp_f32 + v_cvt_pk_bf16_f32 + 2x2 v_permlane32_swap (distinct-value
// operands only; identical inputs tie to one vreg -> vdst==src0 miscompile,
// the r3 inf bug). O^T = V^T.P^T (A=V^T from LDS). setprio(1) around MFMA
// clusters (T5; 4 independent blocks/CU).
// 32x32x16 layouts (m74/m101 verified):
//   A[m = lane&31][k = (lane>>5)*8 + j]
//   B[k = (lane>>5)*8 + j][n = lane&31]
//   C/D: col = lane&31, row = (reg&3) + 8*(reg>>2) + 4*(lane>>5)
__global__ __launch_bounds__(256, 4) void flash_fwd(const float* __restrict__ Q,
                                                    const short* __restrict__ Kb,
                                                    const short* __restrict__ Vt,
                                                    float* __restrict__ O) {
  const int id  = blockIdx.x;
  const int xcd = id & 7;
  const int j   = id >> 3;               // 0..127 within XCD
  const int bh  = xcd * 8 + (j >> 4);
  const int p   = j & 15;                // pair {p, 31-p}
  const int b = bh >> 4, h = bh & 15;
  const int tid = threadIdx.x;
  const int w = tid >> 6;
  const int g = w >> 1;                  // key half-group: keys [k0+32g, +32)
  const int s = w & 1;                   // row strip
  const int lane = tid & 63;
  const int l32 = lane & 31;
  const int hh  = lane >> 5;
  const int h8  = hh * 8;

  // double staging buffers; combine scratch (17.7KB) unions into buf0
  __shared__ __align__(16) char smem[2 * BUFB];
  float* scb = (float*)smem;

  const short* KbBase = Kb + (size_t)bh * L_ * E_;
  const short* VtBase = Vt + (size_t)bh * E_ * L_;

  // staging coords: rows sr, sr+32; cols sc8..sc8+7
  const int sr = tid >> 3;
  const int sc8 = (tid & 7) * 8;

  for (int phase = 0; phase < 2; ++phase) {
    const int qt  = phase ? (31 - p) : p;
    const int q0w = qt * 64 + 32 * s;    // this wave's first q row
    const int nkt = qt + 1;

    // ---- Q B-frags: aQ[ks] covers dims ks*16 + h8 .. +7 (pre-scaled) ----
    bs8 aQ[4];
    {
      const float* qp = Q + (((size_t)b * L_ + q0w + l32) * H_ + h) * E_ + h8;
#pragma unroll
      for (int ks = 0; ks < 4; ++ks) {
        float4 f0 = *(const float4*)(qp + ks * 16);
        float4 f1 = *(const float4*)(qp + ks * 16 + 4);
        bs8 a;
        a[0] = bf16of(f0.x * SCALE_LOG2E); a[1] = bf16of(f0.y * SCALE_LOG2E);
        a[2] = bf16of(f0.z * SCALE_LOG2E); a[3] = bf16of(f0.w * SCALE_LOG2E);
        a[4] = bf16of(f1.x * SCALE_LOG2E); a[5] = bf16of(f1.y * SCALE_LOG2E);
        a[6] = bf16of(f1.z * SCALE_LOG2E); a[7] = bf16of(f1.w * SCALE_LOG2E);
        aQ[ks] = a;
      }
    }

    f32x16 accO[2];            // O^T partial (this g's keys): [dsub]
#pragma unroll
    for (int d = 0; d < 2; ++d)
#pragma unroll
      for (int r = 0; r < 16; ++r) accO[d][r] = 0.f;
    float accL = 0.f;          // denominator partial

    // ---- prologue: stage tile 0 into buf0, prefetch tile 1 ----
    __syncthreads();   // prior-phase scratch reads complete before buf0 reuse
    bs8 pfK[2], pfV[2];
#pragma unroll
    for (int i = 0; i < 2; ++i) {
      pfK[i] = *(const bs8*)(KbBase + (size_t)(sr + 32 * i) * E_ + sc8);
      pfV[i] = *(const bs8*)(VtBase + (size_t)(sr + 32 * i) * L_ + sc8);
    }
    {
      short* nK = (short*)smem;
      short* nV = (short*)(smem + 9216);
#pragma unroll
      for (int i = 0; i < 2; ++i) {
        *(bs8*)&nK[(sr + 32 * i) * KSTR + sc8] = pfK[i];
        *(bs8*)&nV[(sr + 32 * i) * KSTR + sc8] = pfV[i];
      }
    }
    if (nkt > 1) {
#pragma unroll
      for (int i = 0; i < 2; ++i) {
        pfK[i] = *(const bs8*)(KbBase + (size_t)(KT_ + sr + 32 * i) * E_ + sc8);
        pfV[i] = *(const bs8*)(VtBase + (size_t)(sr + 32 * i) * L_ + KT_ + sc8);
      }
    }
    __syncthreads();   // buf0 ready
    int cur = 0;

    for (int kt = 0; kt < nkt; ++kt) {
      short* cK = (short*)(smem + cur * BUFB);
      short* cV = (short*)(smem + cur * BUFB + 9216);
      // write NEXT tile into the other buffer (its last readers finished at
      // the barrier ending iteration kt-1), then prefetch tile kt+2
      if (kt + 1 < nkt) {
        short* nK = (short*)(smem + (cur ^ 1) * BUFB);
        short* nV = (short*)(smem + (cur ^ 1) * BUFB + 9216);
#pragma unroll
        for (int i = 0; i < 2; ++i) {
          *(bs8*)&nK[(sr + 32 * i) * KSTR + sc8] = pfK[i];
          *(bs8*)&nV[(sr + 32 * i) * KSTR + sc8] = pfV[i];
        }
        if (kt + 2 < nkt) {
          const int kn = (kt + 2) * KT_;
#pragma unroll
          for (int i = 0; i < 2; ++i) {
            pfK[i] = *(const bs8*)(KbBase + (size_t)(kn + sr + 32 * i) * E_ + sc8);
            pfV[i] = *(const bs8*)(VtBase + (size_t)(sr + 32 * i) * L_ + kn + sc8);
          }
        }
      }

      const int kb = kt * KT_ + 32 * g;    // this wave's 32-key half
      if (kb <= q0w + 31) {                // not fully masked
        const bool diag = (kb + 31 > q0w);

        // ---- S^T = K.Q^T on this half ----
        f32x16 cc;
#pragma unroll
        for (int r = 0; r < 16; ++r) cc[r] = 0.f;
        __builtin_amdgcn_s_setprio(1);
#pragma unroll
        for (int ks = 0; ks < 4; ++ks) {
          bs8 aK = *(const bs8*)&cK[(32 * g + l32) * KSTR + ks * 16 + h8];
          cc = __builtin_amdgcn_mfma_f32_32x32x16_bf16(aK, aQ[ks], cc, 0, 0, 0);
        }
        __builtin_amdgcn_s_setprio(0);
        if (diag) {
          const int qcol = q0w + l32;
#pragma unroll
          for (int r = 0; r < 16; ++r) {
            const int key = kb + ((r & 3) + 8 * (r >> 2) + 4 * hh);
            if (key > qcol) cc[r] = NEG_INF;
          }
        }
        // ---- exp2 (raw v_exp_f32) in place, denominator, pack (cvt_pk) ----
#pragma unroll
        for (int r = 0; r < 16; ++r) cc[r] = __builtin_amdgcn_exp2f(cc[r]);
        accL += ((((cc[0] + cc[1]) + (cc[2] + cc[3])) + ((cc[4] + cc[5]) + (cc[6] + cc[7]))) +
                 (((cc[8] + cc[9]) + (cc[10] + cc[11])) + ((cc[12] + cc[13]) + (cc[14] + cc[15]))));
        unsigned pk[8];
#pragma unroll
        for (int i = 0; i < 8; ++i)
          asm("v_cvt_pk_bf16_f32 %0, %1, %2"
              : "=v"(pk[i]) : "v"(cc[2 * i]), "v"(cc[2 * i + 1]));
        unsigned w0 = pk[0], w2 = pk[2];
        asm("v_permlane32_swap_b32 %0, %1" : "+v"(w0), "+v"(w2));
        unsigned w1 = pk[1], w3 = pk[3];
        asm("v_permlane32_swap_b32 %0, %1" : "+v"(w1), "+v"(w3));
        unsigned w4 = pk[4], w6 = pk[6];
        asm("v_permlane32_swap_b32 %0, %1" : "+v"(w4), "+v"(w6));
        unsigned w5 = pk[5], w7 = pk[7];
        asm("v_permlane32_swap_b32 %0, %1" : "+v"(w5), "+v"(w7));
        i32x4 f0 = {(int)w0, (int)w1, (int)w2, (int)w3};
        i32x4 f1 = {(int)w4, (int)w5, (int)w6, (int)w7};
        bs8 pB0 = *(bs8*)&f0;
        bs8 pB1 = *(bs8*)&f1;

        // ---- O^T += V^T . P^T (this g's 32 keys) ----
        __builtin_amdgcn_s_setprio(1);
#pragma unroll
        for (int dsub = 0; dsub < 2; ++dsub) {
          bs8 aV0 = *(const bs8*)&cV[(dsub * 32 + l32) * KSTR + 32 * g + h8];
          bs8 aV1 = *(const bs8*)&cV[(dsub * 32 + l32) * KSTR + 32 * g + 16 + h8];
          accO[dsub] = __builtin_amdgcn_mfma_f32_32x32x16_bf16(aV0, pB0, accO[dsub], 0, 0, 0);
          accO[dsub] = __builtin_amdgcn_mfma_f32_32x32x16_bf16(aV1, pB1, accO[dsub], 0, 0, 0);
        }
        __builtin_amdgcn_s_setprio(0);
      }
      __syncthreads();   // readers of buf[cur] done; buf[cur^1] (tile kt+1) ready
      cur ^= 1;
    }

    // ---- combine across g (unnormalized partials add exactly), store ----
    const float Lf = accL + __shfl_xor(accL, 32, 64);
    float* scbO = scb + s * (32 * SCSTR);
    float* scbL = scb + 2 * (32 * SCSTR) + s * 32;
    if (g == 1) {
#pragma unroll
      for (int dsub = 0; dsub < 2; ++dsub)
#pragma unroll
        for (int q4 = 0; q4 < 4; ++q4) {
          f32x4 vv = {accO[dsub][4 * q4 + 0], accO[dsub][4 * q4 + 1],
                      accO[dsub][4 * q4 + 2], accO[dsub][4 * q4 + 3]};
          *(f32x4*)&scbO[(size_t)l32 * SCSTR + dsub * 32 + 8 * q4 + 4 * hh] = vv;
        }
      if (hh == 0) scbL[l32] = Lf;
    }
    __syncthreads();
    if (g == 0) {
      const float inv = 1.f / (Lf + scbL[l32]);
#pragma unroll
      for (int dsub = 0; dsub < 2; ++dsub)
#pragma unroll
        for (int q4 = 0; q4 < 4; ++q4) {
          float* ptr = &scbO[(size_t)l32 * SCSTR + dsub * 32 + 8 * q4 + 4 * hh];
          f32x4 ov = *(const f32x4*)ptr;
          f32x4 vv = {(accO[dsub][4 * q4 + 0] + ov.x) * inv,
                      (accO[dsub][4 * q4 + 1] + ov.y) * inv,
                      (accO[dsub][4 * q4 + 2] + ov.z) * inv,
                      (accO[dsub][4 * q4 + 3] + ov.w) * inv};
          *(f32x4*)ptr = vv;
        }
      // transposed coalesced store: 4 full q-rows per instruction
#pragma unroll
      for (int jj = 0; jj < 8; ++jj) {
        const int qq = jj * 4 + (lane >> 4);
        const int d0 = (lane & 15) * 4;
        f32x4 ov = *(const f32x4*)&scbO[(size_t)qq * SCSTR + d0];
        float* op = O + (((size_t)b * L_ + qt * 64 + 32 * s + qq) * H_ + h) * E_ + d0;
        *(f32x4*)op = ov;
      }
    }
  }
}

extern "C" void kernel_launch(void* const* d_in, const int* in_sizes, int n_in,
                              void* d_out, int out_size, void* d_ws, size_t ws_size,
                              hipStream_t stream) {
  (void)in_sizes; (void)n_in; (void)out_size; (void)ws_size;
  const float* Q = (const float*)d_in[0];
  const float* K = (const float*)d_in[1];
  const float* V = (const float*)d_in[2];
  float* Out = (float*)d_out;
  short* Kb = (short*)d_ws;                              // 16.78 MB
  short* Vt = Kb + (size_t)B_ * H_ * L_ * E_;            // +16.78 MB

  prep<<<1024 + 2048, 256, 0, stream>>>(K, V, Kb, Vt);
  flash_fwd<<<1024, 256, 0, stream>>>(Q, Kb, Vt, Out);
}